// Round 16
// baseline (176.674 us; speedup 1.0000x reference)
//
#include <hip/hip_runtime.h>
#include <hip/hip_bf16.h>

#define N_NODES 50000
#define N_EDGES 400000
#define F_IN    128
#define HID     64
#define HEADS   4
#define HEADC   16
#define C_CLS   10
#define HC      (HEADS * C_CLS)   // 40
#define CST     1e-5f

#define WIN_OFF 0      // [4 nt][4 kt][64 lane]
#define WQ_OFF  1024   // [4 nt][2 kt][64 lane]
#define WK_OFF  1536
#define WV_OFF  2048   // [3 nt][2 kt][64 lane]
#define WB_TOT  2432

typedef short bf16x8 __attribute__((ext_vector_type(8)));
typedef float f32x4  __attribute__((ext_vector_type(4)));
typedef float floatx2 __attribute__((ext_vector_type(2)));

__device__ __forceinline__ unsigned pack_bf16x2(float a, float b) {
    union { __hip_bfloat162 h2; unsigned u; } cv;
    cv.h2.x = __float2bfloat16(a);
    cv.h2.y = __float2bfloat16(b);
    return cv.u;
}
__device__ __forceinline__ float2 bf2_to_f2(unsigned u) {
    union { unsigned x; float f; } a, b;
    a.x = u << 16;
    b.x = u & 0xffff0000u;
    return make_float2(a.f, b.f);
}
union FragU { uint4 u; bf16x8 b; };
__device__ __forceinline__ bf16x8 ldfrag(const uint4* p) { FragU f; f.u = *p; return f.b; }
__device__ __forceinline__ bf16x8 pack8(const float4& a0, const float4& a1) {
    FragU f;
    f.u.x = pack_bf16x2(a0.x, a0.y);
    f.u.y = pack_bf16x2(a0.z, a0.w);
    f.u.z = pack_bf16x2(a1.x, a1.y);
    f.u.w = pack_bf16x2(a1.z, a1.w);
    return f.b;
}
__device__ __forceinline__ void acc_edge_fp8(float kf, uint4 v, float* accM) {
    floatx2 f;
    f = __builtin_amdgcn_cvt_pk_f32_fp8(v.x, false); accM[0] += kf * f[0]; accM[1] += kf * f[1];
    f = __builtin_amdgcn_cvt_pk_f32_fp8(v.x, true);  accM[2] += kf * f[0]; accM[3] += kf * f[1];
    f = __builtin_amdgcn_cvt_pk_f32_fp8(v.y, false); accM[4] += kf * f[0]; accM[5] += kf * f[1];
    f = __builtin_amdgcn_cvt_pk_f32_fp8(v.y, true);  accM[6] += kf * f[0]; accM[7] += kf * f[1];
    f = __builtin_amdgcn_cvt_pk_f32_fp8(v.z, false); accM[8] += kf * f[0]; accM[9] += kf * f[1];
}
__device__ __forceinline__ void acc_edge_fp8_plain(uint2 a, unsigned b, float* accM) {
    floatx2 f;
    f = __builtin_amdgcn_cvt_pk_f32_fp8(a.x, false); accM[0] += f[0]; accM[1] += f[1];
    f = __builtin_amdgcn_cvt_pk_f32_fp8(a.x, true);  accM[2] += f[0]; accM[3] += f[1];
    f = __builtin_amdgcn_cvt_pk_f32_fp8(a.y, false); accM[4] += f[0]; accM[5] += f[1];
    f = __builtin_amdgcn_cvt_pk_f32_fp8(a.y, true);  accM[6] += f[0]; accM[7] += f[1];
    f = __builtin_amdgcn_cvt_pk_f32_fp8(b, false);   accM[8] += f[0]; accM[9] += f[1];
}

// -------------------- weight prep --------------------
__global__ __launch_bounds__(256) void prep_kernel(
    const float* __restrict__ W_in, const float* __restrict__ W_q,
    const float* __restrict__ W_k,  const float* __restrict__ W_v,
    uint4* __restrict__ WB)
{
    const int idx = blockIdx.x * 256 + threadIdx.x;
    if (idx >= WB_TOT) return;
    const int lane = idx & 63;
    const int c = lane & 15, g = lane >> 4;
    const float* src = nullptr;
    if (idx < WQ_OFF) {
        const int f = idx >> 6, nt = f >> 2, kt = f & 3;
        src = W_in + (size_t)(nt * 16 + c) * F_IN + kt * 32 + g * 8;
    } else if (idx < WK_OFF) {
        const int f = (idx - WQ_OFF) >> 6, nt = f >> 1, kt = f & 1;
        src = W_q + (size_t)(nt * 16 + c) * HID + kt * 32 + g * 8;
    } else if (idx < WV_OFF) {
        const int f = (idx - WK_OFF) >> 6, nt = f >> 1, kt = f & 1;
        src = W_k + (size_t)(nt * 16 + c) * HID + kt * 32 + g * 8;
    } else {
        const int f = (idx - WV_OFF) >> 6, nt = f >> 1, kt = f & 1;
        const int row = nt * 16 + c;
        src = (row < HC) ? (W_v + (size_t)row * HID + kt * 32 + g * 8) : nullptr;
    }
    float v[8];
    #pragma unroll
    for (int j = 0; j < 8; ++j) v[j] = src ? src[j] : 0.0f;
    uint4 o;
    o.x = pack_bf16x2(v[0], v[1]);
    o.y = pack_bf16x2(v[2], v[3]);
    o.z = pack_bf16x2(v[4], v[5]);
    o.w = pack_bf16x2(v[6], v[7]);
    WB[idx] = o;
}

// -------------------- projections via MFMA (+ fused V bf16/fp8 pack) --------------------
__global__ __launch_bounds__(256) void proj_kernel(
    const float* __restrict__ feat, const uint4* __restrict__ WB,
    const float* __restrict__ b_in, const float* __restrict__ b_q,
    const float* __restrict__ b_k,  const float* __restrict__ b_v,
    float* __restrict__ Q, __hip_bfloat16* __restrict__ Kf0,
    __hip_bfloat16* __restrict__ V0p, uint4* __restrict__ V0f)
{
    const int w = threadIdx.x >> 6;
    const int l = threadIdx.x & 63;
    const int c = l & 15, g = l >> 4;
    const int nb = blockIdx.x * 64 + w * 16;
    __shared__ float xs[4][16][68];

    f32x4 acc[4];
    #pragma unroll
    for (int nt = 0; nt < 4; ++nt) acc[nt] = (f32x4){0.f, 0.f, 0.f, 0.f};
    int arow = nb + c; if (arow >= N_NODES) arow = N_NODES - 1;
    const float* fbase = feat + (size_t)arow * F_IN + g * 8;
    #pragma unroll
    for (int kt = 0; kt < 4; ++kt) {
        const float4 a0 = *(const float4*)(fbase + kt * 32);
        const float4 a1 = *(const float4*)(fbase + kt * 32 + 4);
        const bf16x8 af = pack8(a0, a1);
        #pragma unroll
        for (int nt = 0; nt < 4; ++nt)
            acc[nt] = __builtin_amdgcn_mfma_f32_16x16x32_bf16(
                af, ldfrag(WB + WIN_OFF + (nt * 4 + kt) * 64 + l), acc[nt], 0, 0, 0);
    }
    #pragma unroll
    for (int nt = 0; nt < 4; ++nt) {
        const int col = nt * 16 + c;
        const float bi = b_in[col];
        #pragma unroll
        for (int i = 0; i < 4; ++i)
            xs[w][g * 4 + i][col] = fmaxf(acc[nt][i] + bi, 0.f);
    }
    __syncthreads();

    f32x4 qa[4], ka[4], va[3];
    #pragma unroll
    for (int nt = 0; nt < 4; ++nt) { qa[nt] = (f32x4){0.f,0.f,0.f,0.f}; ka[nt] = qa[nt]; }
    #pragma unroll
    for (int nt = 0; nt < 3; ++nt) va[nt] = (f32x4){0.f,0.f,0.f,0.f};
    #pragma unroll
    for (int kt = 0; kt < 2; ++kt) {
        const float* xr = &xs[w][c][kt * 32 + g * 8];
        const float4 x0 = *(const float4*)xr;
        const float4 x1 = *(const float4*)(xr + 4);
        const bf16x8 af = pack8(x0, x1);
        #pragma unroll
        for (int nt = 0; nt < 4; ++nt) {
            qa[nt] = __builtin_amdgcn_mfma_f32_16x16x32_bf16(
                af, ldfrag(WB + WQ_OFF + (nt * 2 + kt) * 64 + l), qa[nt], 0, 0, 0);
            ka[nt] = __builtin_amdgcn_mfma_f32_16x16x32_bf16(
                af, ldfrag(WB + WK_OFF + (nt * 2 + kt) * 64 + l), ka[nt], 0, 0, 0);
        }
        #pragma unroll
        for (int nt = 0; nt < 3; ++nt)
            va[nt] = __builtin_amdgcn_mfma_f32_16x16x32_bf16(
                af, ldfrag(WB + WV_OFF + (nt * 2 + kt) * 64 + l), va[nt], 0, 0, 0);
    }

    #pragma unroll
    for (int nt = 0; nt < 4; ++nt) {
        const int col = nt * 16 + c;
        const float bq = b_q[col], bk = b_k[col];
        #pragma unroll
        for (int i = 0; i < 4; ++i) {
            const int node = nb + g * 4 + i;
            if (node < N_NODES) {
                const float zq = qa[nt][i] + bq;
                Q[(size_t)node * HID + col] = (zq > 0.f) ? (zq + 1.f) : expf(zq);
                const float zk = ka[nt][i] + bk;
                Kf0[(size_t)node * HID + col] =
                    __float2bfloat16((zk > 0.f) ? (zk + 1.f) : expf(zk));
            }
        }
    }

    #pragma unroll
    for (int nt = 0; nt < 3; ++nt) {
        const int col = nt * 16 + c;
        if (col < HC) {
            const float bv = b_v[col];
            #pragma unroll
            for (int i = 0; i < 4; ++i)
                xs[w][g * 4 + i][col] = va[nt][i] + bv;
        }
    }
    __syncthreads();

    {
        const int nl = l >> 2, hh = l & 3;
        const int node = nb + nl;
        float v[10];
        #pragma unroll
        for (int j = 0; j < 10; ++j) v[j] = xs[w][nl][hh * 10 + j];
        if (node < N_NODES) {
            unsigned p0 = pack_bf16x2(v[0], v[1]);
            unsigned p1 = pack_bf16x2(v[2], v[3]);
            unsigned p2 = pack_bf16x2(v[4], v[5]);
            unsigned p3 = pack_bf16x2(v[6], v[7]);
            unsigned p4 = pack_bf16x2(v[8], v[9]);
            unsigned* dst = (unsigned*)(V0p + (size_t)node * 64 + hh * 16);
            uint4 o; o.x = p0; o.y = p1; o.z = p2; o.w = p3;
            *(uint4*)dst = o;
            dst[4] = p4;
            int d0 = 0, d1 = 0, d2 = 0;
            d0 = __builtin_amdgcn_cvt_pk_fp8_f32(v[0], v[1], d0, false);
            d0 = __builtin_amdgcn_cvt_pk_fp8_f32(v[2], v[3], d0, true);
            d1 = __builtin_amdgcn_cvt_pk_fp8_f32(v[4], v[5], d1, false);
            d1 = __builtin_amdgcn_cvt_pk_fp8_f32(v[6], v[7], d1, true);
            d2 = __builtin_amdgcn_cvt_pk_fp8_f32(v[8], v[9], d2, false);
            uint4 f8; f8.x = (unsigned)d0; f8.y = (unsigned)d1; f8.z = (unsigned)d2; f8.w = 0u;
            V0f[(size_t)node * 4 + hh] = f8;
        }
    }
}

// -------------------- CSR build --------------------
__global__ __launch_bounds__(256) void hist_kernel(
    const int* __restrict__ ecol, int* __restrict__ deg)
{
    const int e = blockIdx.x * 256 + threadIdx.x;
    if (e < N_EDGES) atomicAdd(&deg[ecol[e]], 1);
}

__global__ __launch_bounds__(256) void offsets_kernel(
    const int* __restrict__ deg, int* __restrict__ rowptr,
    int* __restrict__ cursor, int* __restrict__ gcount)
{
    const int t    = threadIdx.x;
    const int lane = t & 63;
    const int wid  = t >> 6;
    const int n    = blockIdx.x * 256 + t;
    const int d    = (n < N_NODES) ? deg[n] : 0;

    int x = d;
    #pragma unroll
    for (int off = 1; off < 64; off <<= 1) {
        int v = __shfl_up(x, off);
        x += (lane >= off) ? v : 0;
    }

    __shared__ int wsum[4];
    __shared__ int wbase[4];
    __shared__ int bbase;
    if (lane == 63) wsum[wid] = x;
    __syncthreads();
    if (t == 0) {
        int b = 0;
        #pragma unroll
        for (int w = 0; w < 4; ++w) { wbase[w] = b; b += wsum[w]; }
        bbase = atomicAdd(gcount, b);
    }
    __syncthreads();

    if (n < N_NODES) {
        const int excl = bbase + wbase[wid] + (x - d);
        rowptr[n] = excl;
        cursor[n] = excl;
    }
}

__global__ __launch_bounds__(256) void scatter_kernel(
    const int* __restrict__ erow, const int* __restrict__ ecol,
    int* __restrict__ cursor, int* __restrict__ csr_src)
{
    const int e = blockIdx.x * 256 + threadIdx.x;
    if (e < N_EDGES) {
        const int pos = atomicAdd(&cursor[ecol[e]], 1);
        csr_src[pos] = erow[e];
    }
}

// -------------------- hop1 epilogue --------------------
__device__ __forceinline__ void hop1_out(
    int n, int lane, int h, int r, const float* accM, float accK,
    const float* __restrict__ Q, uint2* __restrict__ M1a, unsigned* __restrict__ M1b,
    float* __restrict__ H1, float* __restrict__ Cd1)
{
    int d0 = 0, d1 = 0, d2 = 0;
    d0 = __builtin_amdgcn_cvt_pk_fp8_f32(accM[0], accM[1], d0, false);
    d0 = __builtin_amdgcn_cvt_pk_fp8_f32(accM[2], accM[3], d0, true);
    d1 = __builtin_amdgcn_cvt_pk_fp8_f32(accM[4], accM[5], d1, false);
    d1 = __builtin_amdgcn_cvt_pk_fp8_f32(accM[6], accM[7], d1, true);
    d2 = __builtin_amdgcn_cvt_pk_fp8_f32(accM[8], accM[9], d2, false);
    uint2 sa; sa.x = (unsigned)d0; sa.y = (unsigned)d1;
    M1a[(size_t)n * 64 + lane] = sa;
    M1b[(size_t)n * 64 + lane] =
        ((unsigned)d2 & 0xFFFFu) | (pack_bf16x2(0.f, accK) & 0xFFFF0000u);

    const float q = Q[(size_t)n * HID + lane];
    float pc = q * accK;
    pc += __shfl_xor(pc, 1);
    pc += __shfl_xor(pc, 2);
    pc += __shfl_xor(pc, 4);
    pc += __shfl_xor(pc, 8);
    if (r == 0) Cd1[(size_t)n * HEADS + h] = pc;

    float pj[C_CLS];
    #pragma unroll
    for (int j = 0; j < C_CLS; ++j) {
        pj[j] = q * accM[j];
        pj[j] += __shfl_xor(pj[j], 1);
        pj[j] += __shfl_xor(pj[j], 2);
        pj[j] += __shfl_xor(pj[j], 4);
        pj[j] += __shfl_xor(pj[j], 8);
    }
    if (r < C_CLS) {
        float val = 0.0f;
        #pragma unroll
        for (int j = 0; j < C_CLS; ++j) val = (r == j) ? pj[j] : val;
        H1[(size_t)n * HC + h * C_CLS + r] = val;
    }
}

// -------------------- hop 1: two nodes per wave, interleaved gathers --------------------
__global__ __launch_bounds__(256) void hop1_gather(
    const int* __restrict__ csr_src, const int* __restrict__ rowptr,
    const int* __restrict__ deg,
    const float* __restrict__ Q, const __hip_bfloat16* __restrict__ Kf0,
    const uint4* __restrict__ V0f,
    uint2* __restrict__ M1a, unsigned* __restrict__ M1b,
    float* __restrict__ H1, float* __restrict__ Cd1)
{
    const int sub  = threadIdx.x >> 6;
    const int lane = threadIdx.x & 63;
    const int n0   = blockIdx.x * 8 + sub * 2;
    if (n0 >= N_NODES) return;
    const int n1   = n0 + 1;
    const bool has1 = (n1 < N_NODES);
    const int h = lane >> 4;
    const int r = lane & 15;

    float accM0[C_CLS], accM1[C_CLS];
    #pragma unroll
    for (int j = 0; j < C_CLS; ++j) { accM0[j] = 0.0f; accM1[j] = 0.0f; }
    float accK0 = 0.0f, accK1 = 0.0f;

    const int beg0 = rowptr[n0];
    const int d0   = deg[n0];
    const int beg1 = has1 ? rowptr[n1] : 0;
    const int d1   = has1 ? deg[n1] : 0;
    const int dc0  = (d0 < 64) ? d0 : 64;
    const int dc1  = (d1 < 64) ? d1 : 64;
    int sreg0 = 0, sreg1 = 0;
    if (lane < dc0) sreg0 = csr_src[beg0 + lane];
    if (lane < dc1) sreg1 = csr_src[beg1 + lane];

    int e0 = 0, e1 = 0;
    while (e0 + 2 <= dc0 && e1 + 2 <= dc1) {
        const int sA = __builtin_amdgcn_readlane(sreg0, e0);
        const int sB = __builtin_amdgcn_readlane(sreg0, e0 + 1);
        const int sC = __builtin_amdgcn_readlane(sreg1, e1);
        const int sD = __builtin_amdgcn_readlane(sreg1, e1 + 1);
        const float kfA = __bfloat162float(Kf0[(size_t)sA * HID + lane]);
        const float kfB = __bfloat162float(Kf0[(size_t)sB * HID + lane]);
        const float kfC = __bfloat162float(Kf0[(size_t)sC * HID + lane]);
        const float kfD = __bfloat162float(Kf0[(size_t)sD * HID + lane]);
        const uint4 vA = V0f[(size_t)sA * 4 + h];
        const uint4 vB = V0f[(size_t)sB * 4 + h];
        const uint4 vC = V0f[(size_t)sC * 4 + h];
        const uint4 vD = V0f[(size_t)sD * 4 + h];
        accK0 += kfA + kfB;
        accK1 += kfC + kfD;
        acc_edge_fp8(kfA, vA, accM0);
        acc_edge_fp8(kfB, vB, accM0);
        acc_edge_fp8(kfC, vC, accM1);
        acc_edge_fp8(kfD, vD, accM1);
        e0 += 2; e1 += 2;
    }
    // drain node0
    for (; e0 + 2 <= dc0; e0 += 2) {
        const int sA = __builtin_amdgcn_readlane(sreg0, e0);
        const int sB = __builtin_amdgcn_readlane(sreg0, e0 + 1);
        const float kfA = __bfloat162float(Kf0[(size_t)sA * HID + lane]);
        const float kfB = __bfloat162float(Kf0[(size_t)sB * HID + lane]);
        const uint4 vA = V0f[(size_t)sA * 4 + h];
        const uint4 vB = V0f[(size_t)sB * 4 + h];
        accK0 += kfA + kfB;
        acc_edge_fp8(kfA, vA, accM0);
        acc_edge_fp8(kfB, vB, accM0);
    }
    for (; e0 < dc0; ++e0) {
        const int sA = __builtin_amdgcn_readlane(sreg0, e0);
        const float kfA = __bfloat162float(Kf0[(size_t)sA * HID + lane]);
        const uint4 vA = V0f[(size_t)sA * 4 + h];
        accK0 += kfA;
        acc_edge_fp8(kfA, vA, accM0);
    }
    for (; e0 < d0; ++e0) {
        const int sA = csr_src[beg0 + e0];
        const float kfA = __bfloat162float(Kf0[(size_t)sA * HID + lane]);
        const uint4 vA = V0f[(size_t)sA * 4 + h];
        accK0 += kfA;
        acc_edge_fp8(kfA, vA, accM0);
    }
    // drain node1
    for (; e1 + 2 <= dc1; e1 += 2) {
        const int sC = __builtin_amdgcn_readlane(sreg1, e1);
        const int sD = __builtin_amdgcn_readlane(sreg1, e1 + 1);
        const float kfC = __bfloat162float(Kf0[(size_t)sC * HID + lane]);
        const float kfD = __bfloat162float(Kf0[(size_t)sD * HID + lane]);
        const uint4 vC = V0f[(size_t)sC * 4 + h];
        const uint4 vD = V0f[(size_t)sD * 4 + h];
        accK1 += kfC + kfD;
        acc_edge_fp8(kfC, vC, accM1);
        acc_edge_fp8(kfD, vD, accM1);
    }
    for (; e1 < dc1; ++e1) {
        const int sC = __builtin_amdgcn_readlane(sreg1, e1);
        const float kfC = __bfloat162float(Kf0[(size_t)sC * HID + lane]);
        const uint4 vC = V0f[(size_t)sC * 4 + h];
        accK1 += kfC;
        acc_edge_fp8(kfC, vC, accM1);
    }
    for (; e1 < d1; ++e1) {
        const int sC = csr_src[beg1 + e1];
        const float kfC = __bfloat162float(Kf0[(size_t)sC * HID + lane]);
        const uint4 vC = V0f[(size_t)sC * 4 + h];
        accK1 += kfC;
        acc_edge_fp8(kfC, vC, accM1);
    }

    hop1_out(n0, lane, h, r, accM0, accK0, Q, M1a, M1b, H1, Cd1);
    if (has1) hop1_out(n1, lane, h, r, accM1, accK1, Q, M1a, M1b, H1, Cd1);
}

// -------------------- hop2 epilogue --------------------
__device__ __forceinline__ void hop2_out(
    int n, int lane, int h, int r, const float* accM, float accK,
    const float* __restrict__ Q, float* __restrict__ H2, float* __restrict__ Cd2)
{
    const float q = Q[(size_t)n * HID + lane];
    float pc = q * accK;
    pc += __shfl_xor(pc, 1);
    pc += __shfl_xor(pc, 2);
    pc += __shfl_xor(pc, 4);
    pc += __shfl_xor(pc, 8);
    if (r == 0) Cd2[(size_t)n * HEADS + h] = pc;

    float pj[C_CLS];
    #pragma unroll
    for (int j = 0; j < C_CLS; ++j) {
        pj[j] = q * accM[j];
        pj[j] += __shfl_xor(pj[j], 1);
        pj[j] += __shfl_xor(pj[j], 2);
        pj[j] += __shfl_xor(pj[j], 4);
        pj[j] += __shfl_xor(pj[j], 8);
    }
    if (r < C_CLS) {
        float val = 0.0f;
        #pragma unroll
        for (int j = 0; j < C_CLS; ++j) val = (r == j) ? pj[j] : val;
        H2[(size_t)n * HC + h * C_CLS + r] = val;
    }
}

// -------------------- hop 2: two nodes per wave, interleaved gathers --------------------
__global__ __launch_bounds__(256) void hop2_gather(
    const int* __restrict__ csr_src, const int* __restrict__ rowptr,
    const int* __restrict__ deg,
    const float* __restrict__ Q,
    const uint2* __restrict__ M1a, const unsigned* __restrict__ M1b,
    float* __restrict__ H2, float* __restrict__ Cd2)
{
    const int sub  = threadIdx.x >> 6;
    const int lane = threadIdx.x & 63;
    const int n0   = blockIdx.x * 8 + sub * 2;
    if (n0 >= N_NODES) return;
    const int n1   = n0 + 1;
    const bool has1 = (n1 < N_NODES);
    const int h = lane >> 4;
    const int r = lane & 15;

    float accM0[C_CLS], accM1[C_CLS];
    #pragma unroll
    for (int j = 0; j < C_CLS; ++j) { accM0[j] = 0.0f; accM1[j] = 0.0f; }
    float accK0 = 0.0f, accK1 = 0.0f;

    const int beg0 = rowptr[n0];
    const int d0   = deg[n0];
    const int beg1 = has1 ? rowptr[n1] : 0;
    const int d1   = has1 ? deg[n1] : 0;
    const int dc0  = (d0 < 64) ? d0 : 64;
    const int dc1  = (d1 < 64) ? d1 : 64;
    int sreg0 = 0, sreg1 = 0;
    if (lane < dc0) sreg0 = csr_src[beg0 + lane];
    if (lane < dc1) sreg1 = csr_src[beg1 + lane];

    int e0 = 0, e1 = 0;
    while (e0 + 2 <= dc0 && e1 + 2 <= dc1) {
        const int sA = __builtin_amdgcn_readlane(sreg0, e0);
        const int sB = __builtin_amdgcn_readlane(sreg0, e0 + 1);
        const int sC = __builtin_amdgcn_readlane(sreg1, e1);
        const int sD = __builtin_amdgcn_readlane(sreg1, e1 + 1);
        const uint2 aA = M1a[(size_t)sA * 64 + lane];
        const uint2 aB = M1a[(size_t)sB * 64 + lane];
        const uint2 aC = M1a[(size_t)sC * 64 + lane];
        const uint2 aD = M1a[(size_t)sD * 64 + lane];
        const unsigned bA = M1b[(size_t)sA * 64 + lane];
        const unsigned bB = M1b[(size_t)sB * 64 + lane];
        const unsigned bC = M1b[(size_t)sC * 64 + lane];
        const unsigned bD = M1b[(size_t)sD * 64 + lane];
        accK0 += bf2_to_f2(bA).y + bf2_to_f2(bB).y;
        accK1 += bf2_to_f2(bC).y + bf2_to_f2(bD).y;
        acc_edge_fp8_plain(aA, bA, accM0);
        acc_edge_fp8_plain(aB, bB, accM0);
        acc_edge_fp8_plain(aC, bC, accM1);
        acc_edge_fp8_plain(aD, bD, accM1);
        e0 += 2; e1 += 2;
    }
    for (; e0 + 2 <= dc0; e0 += 2) {
        const int sA = __builtin_amdgcn_readlane(sreg0, e0);
        const int sB = __builtin_amdgcn_readlane(sreg0, e0 + 1);
        const uint2 aA = M1a[(size_t)sA * 64 + lane];
        const uint2 aB = M1a[(size_t)sB * 64 + lane];
        const unsigned bA = M1b[(size_t)sA * 64 + lane];
        const unsigned bB = M1b[(size_t)sB * 64 + lane];
        accK0 += bf2_to_f2(bA).y + bf2_to_f2(bB).y;
        acc_edge_fp8_plain(aA, bA, accM0);
        acc_edge_fp8_plain(aB, bB, accM0);
    }
    for (; e0 < dc0; ++e0) {
        const int sA = __builtin_amdgcn_readlane(sreg0, e0);
        const uint2 aA = M1a[(size_t)sA * 64 + lane];
        const unsigned bA = M1b[(size_t)sA * 64 + lane];
        accK0 += bf2_to_f2(bA).y;
        acc_edge_fp8_plain(aA, bA, accM0);
    }
    for (; e0 < d0; ++e0) {
        const int sA = csr_src[beg0 + e0];
        const uint2 aA = M1a[(size_t)sA * 64 + lane];
        const unsigned bA = M1b[(size_t)sA * 64 + lane];
        accK0 += bf2_to_f2(bA).y;
        acc_edge_fp8_plain(aA, bA, accM0);
    }
    for (; e1 + 2 <= dc1; e1 += 2) {
        const int sC = __builtin_amdgcn_readlane(sreg1, e1);
        const int sD = __builtin_amdgcn_readlane(sreg1, e1 + 1);
        const uint2 aC = M1a[(size_t)sC * 64 + lane];
        const uint2 aD = M1a[(size_t)sD * 64 + lane];
        const unsigned bC = M1b[(size_t)sC * 64 + lane];
        const unsigned bD = M1b[(size_t)sD * 64 + lane];
        accK1 += bf2_to_f2(bC).y + bf2_to_f2(bD).y;
        acc_edge_fp8_plain(aC, bC, accM1);
        acc_edge_fp8_plain(aD, bD, accM1);
    }
    for (; e1 < dc1; ++e1) {
        const int sC = __builtin_amdgcn_readlane(sreg1, e1);
        const uint2 aC = M1a[(size_t)sC * 64 + lane];
        const unsigned bC = M1b[(size_t)sC * 64 + lane];
        accK1 += bf2_to_f2(bC).y;
        acc_edge_fp8_plain(aC, bC, accM1);
    }
    for (; e1 < d1; ++e1) {
        const int sC = csr_src[beg1 + e1];
        const uint2 aC = M1a[(size_t)sC * 64 + lane];
        const unsigned bC = M1b[(size_t)sC * 64 + lane];
        accK1 += bf2_to_f2(bC).y;
        acc_edge_fp8_plain(aC, bC, accM1);
    }

    hop2_out(n0, lane, h, r, accM0, accK0, Q, H2, Cd2);
    if (has1) hop2_out(n1, lane, h, r, accM1, accK1, Q, H2, Cd2);
}

// -------------------- combine + output projection --------------------
__global__ __launch_bounds__(256) void combine_kernel(
    const __hip_bfloat16* __restrict__ V0p,
    const float* __restrict__ H1, const float* __restrict__ Cd1,
    const float* __restrict__ H2, const float* __restrict__ Cd2,
    const float* __restrict__ hopwise, const float* __restrict__ headwise,
    const float* __restrict__ W_out, const float* __restrict__ b_out,
    float* __restrict__ out)
{
    const int n = blockIdx.x * blockDim.x + threadIdx.x;
    if (n >= N_NODES) return;

    float hv[HEADS][2];
    float m0 = -1e30f, m1 = -1e30f;
    #pragma unroll
    for (int h = 0; h < HEADS; ++h) {
        hv[h][0] = headwise[h * 2 + 0];
        hv[h][1] = headwise[h * 2 + 1];
        m0 = fmaxf(m0, hv[h][0]);
        m1 = fmaxf(m1, hv[h][1]);
    }
    float s0 = 0.0f, s1 = 0.0f;
    float e0[HEADS], e1[HEADS];
    #pragma unroll
    for (int h = 0; h < HEADS; ++h) {
        e0[h] = expf(hv[h][0] - m0); s0 += e0[h];
        e1[h] = expf(hv[h][1] - m1); s1 += e1[h];
    }
    const float hw0 = hopwise[0];
    float g1[HEADS], g2[HEADS];
    #pragma unroll
    for (int h = 0; h < HEADS; ++h) {
        g1[h] = hopwise[1] * e0[h] / s0;
        g2[h] = hopwise[2] * e1[h] / s1;
    }

    float hidden[HC];
    #pragma unroll
    for (int h = 0; h < HEADS; ++h) {
        const float icd1 = 1.0f / (Cd1[(size_t)n * HEADS + h] + CST);
        const float icd2 = 1.0f / (Cd2[(size_t)n * HEADS + h] + CST);
        #pragma unroll
        for (int j = 0; j < C_CLS; ++j) {
            const int idx = h * C_CLS + j;
            hidden[idx] = hw0 * __bfloat162float(V0p[(size_t)n * 64 + h * 16 + j])
                        + g1[h] * H1[(size_t)n * HC + idx] * icd1
                        + g2[h] * H2[(size_t)n * HC + idx] * icd2;
        }
    }

    #pragma unroll
    for (int c = 0; c < C_CLS; ++c) {
        float acc = b_out[c];
        const float* w = W_out + c * HC;
        #pragma unroll
        for (int k = 0; k < HC; ++k) acc += w[k] * hidden[k];
        out[(size_t)n * C_CLS + c] = acc;
    }
}

// -------------------- launch --------------------
extern "C" void kernel_launch(void* const* d_in, const int* in_sizes, int n_in,
                              void* d_out, int out_size, void* d_ws, size_t ws_size,
                              hipStream_t stream)
{
    const float* feat     = (const float*)d_in[0];
    const int*   eidx     = (const int*)  d_in[1];
    const float* W_in     = (const float*)d_in[2];
    const float* b_in     = (const float*)d_in[3];
    const float* W_q      = (const float*)d_in[4];
    const float* b_q      = (const float*)d_in[5];
    const float* W_k      = (const float*)d_in[6];
    const float* b_k      = (const float*)d_in[7];
    const float* W_v      = (const float*)d_in[8];
    const float* b_v      = (const float*)d_in[9];
    const float* W_out    = (const float*)d_in[10];
    const float* b_out    = (const float*)d_in[11];
    const float* hopwise  = (const float*)d_in[12];
    const float* headwise = (const float*)d_in[13];
    float* out = (float*)d_out;

    const int* erow = eidx;
    const int* ecol = eidx + N_EDGES;

    float* ws = (float*)d_ws;
    size_t off = 0;
    float* Q    = ws + off; off += (size_t)N_NODES * HID;
    __hip_bfloat16* Kf0 = (__hip_bfloat16*)(ws + off); off += (size_t)N_NODES * HID / 2;
    __hip_bfloat16* V0p = (__hip_bfloat16*)(ws + off); off += (size_t)N_NODES * 32;
    uint4* V0f = (uint4*)(ws + off); off += (size_t)N_NODES * 16;
    uint2* M1a = (uint2*)(ws + off); off += (size_t)N_NODES * 128;
    unsigned* M1b = (unsigned*)(ws + off); off += (size_t)N_NODES * 64;
    float* H1   = ws + off; off += (size_t)N_NODES * HC;
    float* Cd1  = ws + off; off += (size_t)N_NODES * HEADS;
    float* H2   = ws + off; off += (size_t)N_NODES * HC;
    float* Cd2  = ws + off; off += (size_t)N_NODES * HEADS;
    uint4* WB   = (uint4*)(ws + off); off += (size_t)WB_TOT * 4;
    int* iws = (int*)(ws + off);
    int* deg     = iws;
    int* gcount  = iws + N_NODES;
    int* rowptr  = iws + N_NODES + 1;
    int* cursor  = iws + 2 * N_NODES + 1;
    int* csr_src = iws + 3 * N_NODES + 1;

    hipMemsetAsync(deg, 0, (N_NODES + 1) * sizeof(int), stream);

    prep_kernel<<<(WB_TOT + 255) / 256, 256, 0, stream>>>(W_in, W_q, W_k, W_v, WB);

    proj_kernel<<<(N_NODES + 63) / 64, 256, 0, stream>>>(
        feat, WB, b_in, b_q, b_k, b_v, Q, Kf0, V0p, V0f);

    hist_kernel<<<(N_EDGES + 255) / 256, 256, 0, stream>>>(ecol, deg);
    offsets_kernel<<<(N_NODES + 255) / 256, 256, 0, stream>>>(deg, rowptr, cursor, gcount);
    scatter_kernel<<<(N_EDGES + 255) / 256, 256, 0, stream>>>(erow, ecol, cursor, csr_src);

    hop1_gather<<<(N_NODES + 7) / 8, 256, 0, stream>>>(
        csr_src, rowptr, deg, Q, Kf0, V0f, M1a, M1b, H1, Cd1);

    hop2_gather<<<(N_NODES + 7) / 8, 256, 0, stream>>>(
        csr_src, rowptr, deg, Q, M1a, M1b, H2, Cd2);

    combine_kernel<<<(N_NODES + 255) / 256, 256, 0, stream>>>(
        V0p, H1, Cd1, H2, Cd2, hopwise, headwise, W_out, b_out, out);
}

// Round 17
// 171.012 us; speedup vs baseline: 1.0331x; 1.0331x over previous
//
#include <hip/hip_runtime.h>
#include <hip/hip_bf16.h>

#define N_NODES 50000
#define N_EDGES 400000
#define F_IN    128
#define HID     64
#define HEADS   4
#define HEADC   16
#define C_CLS   10
#define HC      (HEADS * C_CLS)   // 40
#define CST     1e-5f

#define WIN_OFF 0      // [4 nt][4 kt][64 lane]
#define WQ_OFF  1024   // [4 nt][2 kt][64 lane]
#define WK_OFF  1536
#define WV_OFF  2048   // [3 nt][2 kt][64 lane]
#define WB_TOT  2432

typedef short bf16x8 __attribute__((ext_vector_type(8)));
typedef float f32x4  __attribute__((ext_vector_type(4)));
typedef float floatx2 __attribute__((ext_vector_type(2)));

__device__ __forceinline__ unsigned pack_bf16x2(float a, float b) {
    union { __hip_bfloat162 h2; unsigned u; } cv;
    cv.h2.x = __float2bfloat16(a);
    cv.h2.y = __float2bfloat16(b);
    return cv.u;
}
__device__ __forceinline__ float2 bf2_to_f2(unsigned u) {
    union { unsigned x; float f; } a, b;
    a.x = u << 16;
    b.x = u & 0xffff0000u;
    return make_float2(a.f, b.f);
}
union FragU { uint4 u; bf16x8 b; };
__device__ __forceinline__ bf16x8 ldfrag(const uint4* p) { FragU f; f.u = *p; return f.b; }
__device__ __forceinline__ bf16x8 pack8(const float4& a0, const float4& a1) {
    FragU f;
    f.u.x = pack_bf16x2(a0.x, a0.y);
    f.u.y = pack_bf16x2(a0.z, a0.w);
    f.u.z = pack_bf16x2(a1.x, a1.y);
    f.u.w = pack_bf16x2(a1.z, a1.w);
    return f.b;
}
// fp8 edge-accumulate: 10 fp8 in v.{x,y,z}, scaled by kf into accM[10]
__device__ __forceinline__ void acc_edge_fp8(float kf, uint4 v, float* accM) {
    floatx2 f;
    f = __builtin_amdgcn_cvt_pk_f32_fp8(v.x, false); accM[0] += kf * f[0]; accM[1] += kf * f[1];
    f = __builtin_amdgcn_cvt_pk_f32_fp8(v.x, true);  accM[2] += kf * f[0]; accM[3] += kf * f[1];
    f = __builtin_amdgcn_cvt_pk_f32_fp8(v.y, false); accM[4] += kf * f[0]; accM[5] += kf * f[1];
    f = __builtin_amdgcn_cvt_pk_f32_fp8(v.y, true);  accM[6] += kf * f[0]; accM[7] += kf * f[1];
    f = __builtin_amdgcn_cvt_pk_f32_fp8(v.z, false); accM[8] += kf * f[0]; accM[9] += kf * f[1];
}
__device__ __forceinline__ void acc_edge_fp8_plain(uint4 v, float* accM) {
    floatx2 f;
    f = __builtin_amdgcn_cvt_pk_f32_fp8(v.x, false); accM[0] += f[0]; accM[1] += f[1];
    f = __builtin_amdgcn_cvt_pk_f32_fp8(v.x, true);  accM[2] += f[0]; accM[3] += f[1];
    f = __builtin_amdgcn_cvt_pk_f32_fp8(v.y, false); accM[4] += f[0]; accM[5] += f[1];
    f = __builtin_amdgcn_cvt_pk_f32_fp8(v.y, true);  accM[6] += f[0]; accM[7] += f[1];
    f = __builtin_amdgcn_cvt_pk_f32_fp8(v.z, false); accM[8] += f[0]; accM[9] += f[1];
}

// -------------------- weight prep: f32 -> bf16 B-fragments --------------------
__global__ __launch_bounds__(256) void prep_kernel(
    const float* __restrict__ W_in, const float* __restrict__ W_q,
    const float* __restrict__ W_k,  const float* __restrict__ W_v,
    uint4* __restrict__ WB)
{
    const int idx = blockIdx.x * 256 + threadIdx.x;
    if (idx >= WB_TOT) return;
    const int lane = idx & 63;
    const int c = lane & 15, g = lane >> 4;
    const float* src = nullptr;
    if (idx < WQ_OFF) {
        const int f = idx >> 6, nt = f >> 2, kt = f & 3;
        src = W_in + (size_t)(nt * 16 + c) * F_IN + kt * 32 + g * 8;
    } else if (idx < WK_OFF) {
        const int f = (idx - WQ_OFF) >> 6, nt = f >> 1, kt = f & 1;
        src = W_q + (size_t)(nt * 16 + c) * HID + kt * 32 + g * 8;
    } else if (idx < WV_OFF) {
        const int f = (idx - WK_OFF) >> 6, nt = f >> 1, kt = f & 1;
        src = W_k + (size_t)(nt * 16 + c) * HID + kt * 32 + g * 8;
    } else {
        const int f = (idx - WV_OFF) >> 6, nt = f >> 1, kt = f & 1;
        const int row = nt * 16 + c;
        src = (row < HC) ? (W_v + (size_t)row * HID + kt * 32 + g * 8) : nullptr;
    }
    float v[8];
    #pragma unroll
    for (int j = 0; j < 8; ++j) v[j] = src ? src[j] : 0.0f;
    uint4 o;
    o.x = pack_bf16x2(v[0], v[1]);
    o.y = pack_bf16x2(v[2], v[3]);
    o.z = pack_bf16x2(v[4], v[5]);
    o.w = pack_bf16x2(v[6], v[7]);
    WB[idx] = o;
}

// -------------------- projections via MFMA (+ fused V bf16/fp8 pack) --------------------
__global__ __launch_bounds__(256) void proj_kernel(
    const float* __restrict__ feat, const uint4* __restrict__ WB,
    const float* __restrict__ b_in, const float* __restrict__ b_q,
    const float* __restrict__ b_k,  const float* __restrict__ b_v,
    float* __restrict__ Q, __hip_bfloat16* __restrict__ Kf0,
    __hip_bfloat16* __restrict__ V0p, uint4* __restrict__ V0f)
{
    const int w = threadIdx.x >> 6;
    const int l = threadIdx.x & 63;
    const int c = l & 15, g = l >> 4;
    const int nb = blockIdx.x * 64 + w * 16;
    __shared__ float xs[4][16][68];

    f32x4 acc[4];
    #pragma unroll
    for (int nt = 0; nt < 4; ++nt) acc[nt] = (f32x4){0.f, 0.f, 0.f, 0.f};
    int arow = nb + c; if (arow >= N_NODES) arow = N_NODES - 1;
    const float* fbase = feat + (size_t)arow * F_IN + g * 8;
    #pragma unroll
    for (int kt = 0; kt < 4; ++kt) {
        const float4 a0 = *(const float4*)(fbase + kt * 32);
        const float4 a1 = *(const float4*)(fbase + kt * 32 + 4);
        const bf16x8 af = pack8(a0, a1);
        #pragma unroll
        for (int nt = 0; nt < 4; ++nt)
            acc[nt] = __builtin_amdgcn_mfma_f32_16x16x32_bf16(
                af, ldfrag(WB + WIN_OFF + (nt * 4 + kt) * 64 + l), acc[nt], 0, 0, 0);
    }
    #pragma unroll
    for (int nt = 0; nt < 4; ++nt) {
        const int col = nt * 16 + c;
        const float bi = b_in[col];
        #pragma unroll
        for (int i = 0; i < 4; ++i)
            xs[w][g * 4 + i][col] = fmaxf(acc[nt][i] + bi, 0.f);
    }
    __syncthreads();

    f32x4 qa[4], ka[4], va[3];
    #pragma unroll
    for (int nt = 0; nt < 4; ++nt) { qa[nt] = (f32x4){0.f,0.f,0.f,0.f}; ka[nt] = qa[nt]; }
    #pragma unroll
    for (int nt = 0; nt < 3; ++nt) va[nt] = (f32x4){0.f,0.f,0.f,0.f};
    #pragma unroll
    for (int kt = 0; kt < 2; ++kt) {
        const float* xr = &xs[w][c][kt * 32 + g * 8];
        const float4 x0 = *(const float4*)xr;
        const float4 x1 = *(const float4*)(xr + 4);
        const bf16x8 af = pack8(x0, x1);
        #pragma unroll
        for (int nt = 0; nt < 4; ++nt) {
            qa[nt] = __builtin_amdgcn_mfma_f32_16x16x32_bf16(
                af, ldfrag(WB + WQ_OFF + (nt * 2 + kt) * 64 + l), qa[nt], 0, 0, 0);
            ka[nt] = __builtin_amdgcn_mfma_f32_16x16x32_bf16(
                af, ldfrag(WB + WK_OFF + (nt * 2 + kt) * 64 + l), ka[nt], 0, 0, 0);
        }
        #pragma unroll
        for (int nt = 0; nt < 3; ++nt)
            va[nt] = __builtin_amdgcn_mfma_f32_16x16x32_bf16(
                af, ldfrag(WB + WV_OFF + (nt * 2 + kt) * 64 + l), va[nt], 0, 0, 0);
    }

    // Q / Kf0 epilogue
    #pragma unroll
    for (int nt = 0; nt < 4; ++nt) {
        const int col = nt * 16 + c;
        const float bq = b_q[col], bk = b_k[col];
        #pragma unroll
        for (int i = 0; i < 4; ++i) {
            const int node = nb + g * 4 + i;
            if (node < N_NODES) {
                const float zq = qa[nt][i] + bq;
                Q[(size_t)node * HID + col] = (zq > 0.f) ? (zq + 1.f) : expf(zq);
                const float zk = ka[nt][i] + bk;
                Kf0[(size_t)node * HID + col] =
                    __float2bfloat16((zk > 0.f) ? (zk + 1.f) : expf(zk));
            }
        }
    }

    // stage V (f32) to xs (wave-local), then pack per (node, head) thread
    #pragma unroll
    for (int nt = 0; nt < 3; ++nt) {
        const int col = nt * 16 + c;
        if (col < HC) {
            const float bv = b_v[col];
            #pragma unroll
            for (int i = 0; i < 4; ++i)
                xs[w][g * 4 + i][col] = va[nt][i] + bv;
        }
    }
    __syncthreads();   // conservative (wave-local in practice)

    {
        const int nl = l >> 2, hh = l & 3;
        const int node = nb + nl;
        float v[10];
        #pragma unroll
        for (int j = 0; j < 10; ++j) v[j] = xs[w][nl][hh * 10 + j];
        if (node < N_NODES) {
            unsigned p0 = pack_bf16x2(v[0], v[1]);
            unsigned p1 = pack_bf16x2(v[2], v[3]);
            unsigned p2 = pack_bf16x2(v[4], v[5]);
            unsigned p3 = pack_bf16x2(v[6], v[7]);
            unsigned p4 = pack_bf16x2(v[8], v[9]);
            unsigned* dst = (unsigned*)(V0p + (size_t)node * 64 + hh * 16);
            uint4 o; o.x = p0; o.y = p1; o.z = p2; o.w = p3;
            *(uint4*)dst = o;
            dst[4] = p4;
            int d0 = 0, d1 = 0, d2 = 0;
            d0 = __builtin_amdgcn_cvt_pk_fp8_f32(v[0], v[1], d0, false);
            d0 = __builtin_amdgcn_cvt_pk_fp8_f32(v[2], v[3], d0, true);
            d1 = __builtin_amdgcn_cvt_pk_fp8_f32(v[4], v[5], d1, false);
            d1 = __builtin_amdgcn_cvt_pk_fp8_f32(v[6], v[7], d1, true);
            d2 = __builtin_amdgcn_cvt_pk_fp8_f32(v[8], v[9], d2, false);
            uint4 f8; f8.x = (unsigned)d0; f8.y = (unsigned)d1; f8.z = (unsigned)d2; f8.w = 0u;
            V0f[(size_t)node * 4 + hh] = f8;
        }
    }
}

// -------------------- CSR build --------------------
__global__ __launch_bounds__(256) void hist_kernel(
    const int* __restrict__ ecol, int* __restrict__ deg)
{
    const int e = blockIdx.x * 256 + threadIdx.x;
    if (e < N_EDGES) atomicAdd(&deg[ecol[e]], 1);
}

__global__ __launch_bounds__(256) void offsets_kernel(
    const int* __restrict__ deg, int* __restrict__ rowptr,
    int* __restrict__ cursor, int* __restrict__ gcount)
{
    const int t    = threadIdx.x;
    const int lane = t & 63;
    const int wid  = t >> 6;
    const int n    = blockIdx.x * 256 + t;
    const int d    = (n < N_NODES) ? deg[n] : 0;

    int x = d;
    #pragma unroll
    for (int off = 1; off < 64; off <<= 1) {
        int v = __shfl_up(x, off);
        x += (lane >= off) ? v : 0;
    }

    __shared__ int wsum[4];
    __shared__ int wbase[4];
    __shared__ int bbase;
    if (lane == 63) wsum[wid] = x;
    __syncthreads();
    if (t == 0) {
        int b = 0;
        #pragma unroll
        for (int w = 0; w < 4; ++w) { wbase[w] = b; b += wsum[w]; }
        bbase = atomicAdd(gcount, b);
    }
    __syncthreads();

    if (n < N_NODES) {
        const int excl = bbase + wbase[wid] + (x - d);
        rowptr[n] = excl;
        cursor[n] = excl;
    }
}

__global__ __launch_bounds__(256) void scatter_kernel(
    const int* __restrict__ erow, const int* __restrict__ ecol,
    int* __restrict__ cursor, int* __restrict__ csr_src)
{
    const int e = blockIdx.x * 256 + threadIdx.x;
    if (e < N_EDGES) {
        const int pos = atomicAdd(&cursor[ecol[e]], 1);
        csr_src[pos] = erow[e];
    }
}

// -------------------- hop 1: readlane-CSR gather --------------------
// M1a: [n][64] uint2 (fp8 j0..7). M1b: [n][64] dword = fp8 j8,j9 | Kf1(bf16)<<16.
__global__ __launch_bounds__(256) void hop1_gather(
    const int* __restrict__ csr_src, const int* __restrict__ rowptr,
    const int* __restrict__ deg,
    const float* __restrict__ Q, const __hip_bfloat16* __restrict__ Kf0,
    const uint4* __restrict__ V0f,
    uint2* __restrict__ M1a, unsigned* __restrict__ M1b,
    float* __restrict__ H1, float* __restrict__ Cd1)
{
    const int sub  = threadIdx.x >> 6;
    const int lane = threadIdx.x & 63;
    const int n    = blockIdx.x * 4 + sub;
    if (n >= N_NODES) return;
    const int h = lane >> 4;
    const int r = lane & 15;

    float accM[C_CLS];
    #pragma unroll
    for (int j = 0; j < C_CLS; ++j) accM[j] = 0.0f;
    float accK = 0.0f;

    const int beg = rowptr[n];
    const int d   = deg[n];
    const int dc  = (d < 64) ? d : 64;
    int sreg = 0;
    if (lane < dc) sreg = csr_src[beg + lane];   // ONE coalesced vmem for all indices

    int e = 0;
    for (; e + 4 <= dc; e += 4) {
        const int s0 = __builtin_amdgcn_readlane(sreg, e);
        const int s1 = __builtin_amdgcn_readlane(sreg, e + 1);
        const int s2 = __builtin_amdgcn_readlane(sreg, e + 2);
        const int s3 = __builtin_amdgcn_readlane(sreg, e + 3);
        const float kf0 = __bfloat162float(Kf0[(size_t)s0 * HID + lane]);
        const float kf1 = __bfloat162float(Kf0[(size_t)s1 * HID + lane]);
        const float kf2 = __bfloat162float(Kf0[(size_t)s2 * HID + lane]);
        const float kf3 = __bfloat162float(Kf0[(size_t)s3 * HID + lane]);
        const uint4 v0 = V0f[(size_t)s0 * 4 + h];
        const uint4 v1 = V0f[(size_t)s1 * 4 + h];
        const uint4 v2 = V0f[(size_t)s2 * 4 + h];
        const uint4 v3 = V0f[(size_t)s3 * 4 + h];
        accK += (kf0 + kf1) + (kf2 + kf3);
        acc_edge_fp8(kf0, v0, accM);
        acc_edge_fp8(kf1, v1, accM);
        acc_edge_fp8(kf2, v2, accM);
        acc_edge_fp8(kf3, v3, accM);
    }
    for (; e < dc; ++e) {
        const int s0 = __builtin_amdgcn_readlane(sreg, e);
        const float kf = __bfloat162float(Kf0[(size_t)s0 * HID + lane]);
        const uint4 v0 = V0f[(size_t)s0 * 4 + h];
        accK += kf;
        acc_edge_fp8(kf, v0, accM);
    }
    for (; e < d; ++e) {                        // deg>64 overflow (essentially never)
        const int s0 = csr_src[beg + e];
        const float kf = __bfloat162float(Kf0[(size_t)s0 * HID + lane]);
        const uint4 v0 = V0f[(size_t)s0 * 4 + h];
        accK += kf;
        acc_edge_fp8(kf, v0, accM);
    }

    // outputs
    int d0 = 0, d1 = 0, d2 = 0;
    d0 = __builtin_amdgcn_cvt_pk_fp8_f32(accM[0], accM[1], d0, false);
    d0 = __builtin_amdgcn_cvt_pk_fp8_f32(accM[2], accM[3], d0, true);
    d1 = __builtin_amdgcn_cvt_pk_fp8_f32(accM[4], accM[5], d1, false);
    d1 = __builtin_amdgcn_cvt_pk_fp8_f32(accM[6], accM[7], d1, true);
    d2 = __builtin_amdgcn_cvt_pk_fp8_f32(accM[8], accM[9], d2, false);
    uint2 sa; sa.x = (unsigned)d0; sa.y = (unsigned)d1;
    M1a[(size_t)n * 64 + lane] = sa;
    M1b[(size_t)n * 64 + lane] =
        ((unsigned)d2 & 0xFFFFu) | (pack_bf16x2(0.f, accK) & 0xFFFF0000u);

    const float q = Q[(size_t)n * HID + lane];
    float pc = q * accK;
    pc += __shfl_xor(pc, 1);
    pc += __shfl_xor(pc, 2);
    pc += __shfl_xor(pc, 4);
    pc += __shfl_xor(pc, 8);
    if (r == 0) Cd1[(size_t)n * HEADS + h] = pc;

    float pj[C_CLS];
    #pragma unroll
    for (int j = 0; j < C_CLS; ++j) {
        pj[j] = q * accM[j];
        pj[j] += __shfl_xor(pj[j], 1);
        pj[j] += __shfl_xor(pj[j], 2);
        pj[j] += __shfl_xor(pj[j], 4);
        pj[j] += __shfl_xor(pj[j], 8);
    }
    if (r < C_CLS) {
        float val = 0.0f;
        #pragma unroll
        for (int j = 0; j < C_CLS; ++j) val = (r == j) ? pj[j] : val;
        H1[(size_t)n * HC + h * C_CLS + r] = val;
    }
}

// -------------------- hop 2: readlane-CSR gather --------------------
__global__ __launch_bounds__(256) void hop2_gather(
    const int* __restrict__ csr_src, const int* __restrict__ rowptr,
    const int* __restrict__ deg,
    const float* __restrict__ Q,
    const uint2* __restrict__ M1a, const unsigned* __restrict__ M1b,
    float* __restrict__ H2, float* __restrict__ Cd2)
{
    const int sub  = threadIdx.x >> 6;
    const int lane = threadIdx.x & 63;
    const int n    = blockIdx.x * 4 + sub;
    if (n >= N_NODES) return;
    const int h = lane >> 4;
    const int r = lane & 15;

    const float q = Q[(size_t)n * HID + lane];
    float accM[C_CLS];
    #pragma unroll
    for (int j = 0; j < C_CLS; ++j) accM[j] = 0.0f;
    float accK = 0.0f;

    const int beg = rowptr[n];
    const int d   = deg[n];
    const int dc  = (d < 64) ? d : 64;
    int sreg = 0;
    if (lane < dc) sreg = csr_src[beg + lane];

    int e = 0;
    for (; e + 4 <= dc; e += 4) {
        const int s0 = __builtin_amdgcn_readlane(sreg, e);
        const int s1 = __builtin_amdgcn_readlane(sreg, e + 1);
        const int s2 = __builtin_amdgcn_readlane(sreg, e + 2);
        const int s3 = __builtin_amdgcn_readlane(sreg, e + 3);
        const uint2 a0 = M1a[(size_t)s0 * 64 + lane];
        const uint2 a1 = M1a[(size_t)s1 * 64 + lane];
        const uint2 a2 = M1a[(size_t)s2 * 64 + lane];
        const uint2 a3 = M1a[(size_t)s3 * 64 + lane];
        const unsigned b0 = M1b[(size_t)s0 * 64 + lane];
        const unsigned b1 = M1b[(size_t)s1 * 64 + lane];
        const unsigned b2 = M1b[(size_t)s2 * 64 + lane];
        const unsigned b3 = M1b[(size_t)s3 * 64 + lane];
        accK += bf2_to_f2(b0).y + bf2_to_f2(b1).y + bf2_to_f2(b2).y + bf2_to_f2(b3).y;
        uint4 w;
        w.x = a0.x; w.y = a0.y; w.z = b0; acc_edge_fp8_plain(w, accM);
        w.x = a1.x; w.y = a1.y; w.z = b1; acc_edge_fp8_plain(w, accM);
        w.x = a2.x; w.y = a2.y; w.z = b2; acc_edge_fp8_plain(w, accM);
        w.x = a3.x; w.y = a3.y; w.z = b3; acc_edge_fp8_plain(w, accM);
    }
    for (; e < dc; ++e) {
        const int s0 = __builtin_amdgcn_readlane(sreg, e);
        const uint2 a0 = M1a[(size_t)s0 * 64 + lane];
        const unsigned b0 = M1b[(size_t)s0 * 64 + lane];
        accK += bf2_to_f2(b0).y;
        uint4 w; w.x = a0.x; w.y = a0.y; w.z = b0;
        acc_edge_fp8_plain(w, accM);
    }
    for (; e < d; ++e) {
        const int s0 = csr_src[beg + e];
        const uint2 a0 = M1a[(size_t)s0 * 64 + lane];
        const unsigned b0 = M1b[(size_t)s0 * 64 + lane];
        accK += bf2_to_f2(b0).y;
        uint4 w; w.x = a0.x; w.y = a0.y; w.z = b0;
        acc_edge_fp8_plain(w, accM);
    }

    float pc = q * accK;
    pc += __shfl_xor(pc, 1);
    pc += __shfl_xor(pc, 2);
    pc += __shfl_xor(pc, 4);
    pc += __shfl_xor(pc, 8);
    if (r == 0) Cd2[(size_t)n * HEADS + h] = pc;

    float pj[C_CLS];
    #pragma unroll
    for (int j = 0; j < C_CLS; ++j) {
        pj[j] = q * accM[j];
        pj[j] += __shfl_xor(pj[j], 1);
        pj[j] += __shfl_xor(pj[j], 2);
        pj[j] += __shfl_xor(pj[j], 4);
        pj[j] += __shfl_xor(pj[j], 8);
    }
    if (r < C_CLS) {
        float val = 0.0f;
        #pragma unroll
        for (int j = 0; j < C_CLS; ++j) val = (r == j) ? pj[j] : val;
        H2[(size_t)n * HC + h * C_CLS + r] = val;
    }
}

// -------------------- combine + output projection --------------------
__global__ __launch_bounds__(256) void combine_kernel(
    const __hip_bfloat16* __restrict__ V0p,
    const float* __restrict__ H1, const float* __restrict__ Cd1,
    const float* __restrict__ H2, const float* __restrict__ Cd2,
    const float* __restrict__ hopwise, const float* __restrict__ headwise,
    const float* __restrict__ W_out, const float* __restrict__ b_out,
    float* __restrict__ out)
{
    const int n = blockIdx.x * blockDim.x + threadIdx.x;
    if (n >= N_NODES) return;

    float hv[HEADS][2];
    float m0 = -1e30f, m1 = -1e30f;
    #pragma unroll
    for (int h = 0; h < HEADS; ++h) {
        hv[h][0] = headwise[h * 2 + 0];
        hv[h][1] = headwise[h * 2 + 1];
        m0 = fmaxf(m0, hv[h][0]);
        m1 = fmaxf(m1, hv[h][1]);
    }
    float s0 = 0.0f, s1 = 0.0f;
    float e0[HEADS], e1[HEADS];
    #pragma unroll
    for (int h = 0; h < HEADS; ++h) {
        e0[h] = expf(hv[h][0] - m0); s0 += e0[h];
        e1[h] = expf(hv[h][1] - m1); s1 += e1[h];
    }
    const float hw0 = hopwise[0];
    float g1[HEADS], g2[HEADS];
    #pragma unroll
    for (int h = 0; h < HEADS; ++h) {
        g1[h] = hopwise[1] * e0[h] / s0;
        g2[h] = hopwise[2] * e1[h] / s1;
    }

    float hidden[HC];
    #pragma unroll
    for (int h = 0; h < HEADS; ++h) {
        const float icd1 = 1.0f / (Cd1[(size_t)n * HEADS + h] + CST);
        const float icd2 = 1.0f / (Cd2[(size_t)n * HEADS + h] + CST);
        #pragma unroll
        for (int j = 0; j < C_CLS; ++j) {
            const int idx = h * C_CLS + j;
            hidden[idx] = hw0 * __bfloat162float(V0p[(size_t)n * 64 + h * 16 + j])
                        + g1[h] * H1[(size_t)n * HC + idx] * icd1
                        + g2[h] * H2[(size_t)n * HC + idx] * icd2;
        }
    }

    #pragma unroll
    for (int c = 0; c < C_CLS; ++c) {
        float acc = b_out[c];
        const float* w = W_out + c * HC;
        #pragma unroll
        for (int k = 0; k < HC; ++k) acc += w[k] * hidden[k];
        out[(size_t)n * C_CLS + c] = acc;
    }
}

// -------------------- launch --------------------
extern "C" void kernel_launch(void* const* d_in, const int* in_sizes, int n_in,
                              void* d_out, int out_size, void* d_ws, size_t ws_size,
                              hipStream_t stream)
{
    const float* feat     = (const float*)d_in[0];
    const int*   eidx     = (const int*)  d_in[1];
    const float* W_in     = (const float*)d_in[2];
    const float* b_in     = (const float*)d_in[3];
    const float* W_q      = (const float*)d_in[4];
    const float* b_q      = (const float*)d_in[5];
    const float* W_k      = (const float*)d_in[6];
    const float* b_k      = (const float*)d_in[7];
    const float* W_v      = (const float*)d_in[8];
    const float* b_v      = (const float*)d_in[9];
    const float* W_out    = (const float*)d_in[10];
    const float* b_out    = (const float*)d_in[11];
    const float* hopwise  = (const float*)d_in[12];
    const float* headwise = (const float*)d_in[13];
    float* out = (float*)d_out;

    const int* erow = eidx;
    const int* ecol = eidx + N_EDGES;

    float* ws = (float*)d_ws;
    size_t off = 0;
    float* Q    = ws + off; off += (size_t)N_NODES * HID;
    __hip_bfloat16* Kf0 = (__hip_bfloat16*)(ws + off); off += (size_t)N_NODES * HID / 2;
    __hip_bfloat16* V0p = (__hip_bfloat16*)(ws + off); off += (size_t)N_NODES * 32;
    uint4* V0f = (uint4*)(ws + off); off += (size_t)N_NODES * 16;
    uint2* M1a = (uint2*)(ws + off); off += (size_t)N_NODES * 128;
    unsigned* M1b = (unsigned*)(ws + off); off += (size_t)N_NODES * 64;
    float* H1   = ws + off; off += (size_t)N_NODES * HC;
    float* Cd1  = ws + off; off += (size_t)N_NODES * HEADS;
    float* H2   = ws + off; off += (size_t)N_NODES * HC;
    float* Cd2  = ws + off; off += (size_t)N_NODES * HEADS;
    uint4* WB   = (uint4*)(ws + off); off += (size_t)WB_TOT * 4;
    int* iws = (int*)(ws + off);
    int* deg     = iws;
    int* gcount  = iws + N_NODES;
    int* rowptr  = iws + N_NODES + 1;
    int* cursor  = iws + 2 * N_NODES + 1;
    int* csr_src = iws + 3 * N_NODES + 1;

    hipMemsetAsync(deg, 0, (N_NODES + 1) * sizeof(int), stream);

    prep_kernel<<<(WB_TOT + 255) / 256, 256, 0, stream>>>(W_in, W_q, W_k, W_v, WB);

    proj_kernel<<<(N_NODES + 63) / 64, 256, 0, stream>>>(
        feat, WB, b_in, b_q, b_k, b_v, Q, Kf0, V0p, V0f);

    hist_kernel<<<(N_EDGES + 255) / 256, 256, 0, stream>>>(ecol, deg);
    offsets_kernel<<<(N_NODES + 255) / 256, 256, 0, stream>>>(deg, rowptr, cursor, gcount);
    scatter_kernel<<<(N_EDGES + 255) / 256, 256, 0, stream>>>(erow, ecol, cursor, csr_src);

    hop1_gather<<<(N_NODES + 3) / 4, 256, 0, stream>>>(
        csr_src, rowptr, deg, Q, Kf0, V0f, M1a, M1b, H1, Cd1);

    hop2_gather<<<(N_NODES + 3) / 4, 256, 0, stream>>>(
        csr_src, rowptr, deg, Q, M1a, M1b, H2, Cd2);

    combine_kernel<<<(N_NODES + 255) / 256, 256, 0, stream>>>(
        V0p, H1, Cd1, H2, Cd2, hopwise, headwise, W_out, b_out, out);
}